// Round 11
// baseline (50.067 us; speedup 1.0000x reference)
//
#include <hip/hip_runtime.h>
#include <cmath>

typedef unsigned short u16;
typedef __bf16 bf16x8 __attribute__((ext_vector_type(8)));
typedef float f32x4 __attribute__((ext_vector_type(4)));
typedef unsigned short u16x4 __attribute__((ext_vector_type(4)));

#define BATCH 16384
#define NTREE 32
#define NINT 63
#define NLEAF 64
#define FDIM 256
#define MT 128     // batch rows per block

typedef __attribute__((address_space(3))) void lvoid;
typedef __attribute__((address_space(1))) const void gvoid;
__device__ __forceinline__ void gload16(const void* g, void* l) {
    // DMA 16B/lane global->LDS; LDS dest = wave-uniform base + lane*16 (HW rule)
    __builtin_amdgcn_global_load_lds((gvoid*)g, (lvoid*)l, 16, 0, 0);
}

__device__ __forceinline__ u16 f2bf(float f) {
    unsigned int x = __float_as_uint(f);
    x += 0x7fffu + ((x >> 16) & 1u);   // round-to-nearest-even
    return (u16)(x >> 16);
}

// D-row slot s (0..63) -> heap node id (R6-verified permutation).
__device__ __forceinline__ int slot2node(int slot) {
    int lg = (slot >> 2) & 3;
    int v = ((slot >> 4) << 2) | (slot & 3);
    if (v == 0)  return (lg & 1) ? (1 + (lg >> 1)) : 0;
    if (v == 1)  return 3 + lg;
    if (v < 4)   return 7 + 2 * lg + (v - 2);
    if (v < 8)   return 15 + 4 * lg + (v - 4);
    return 31 + 8 * lg + (v - 8);
}

__global__ void convert_kernel(const float* __restrict__ x, const float* __restrict__ W,
                               const float* __restrict__ b,
                               u16* __restrict__ xb, u16* __restrict__ Wb,
                               float* __restrict__ bperm) {
    int idx = blockIdx.x * blockDim.x + threadIdx.x;
    int stride = gridDim.x * blockDim.x;
    const int NXQ = BATCH * FDIM / 4;
    for (int i = idx; i < NXQ; i += stride) {
        float4 v = ((const float4*)x)[i];
        u16x4 o = { f2bf(v.x), f2bf(v.y), f2bf(v.z), f2bf(v.w) };
        ((u16x4*)xb)[i] = o;
    }
    // Wb: [tree][64 slots (permuted nodes, root duplicated)][256 features]
    const int NWQ = NTREE * NLEAF * FDIM / 4;
    for (int i = idx; i < NWQ; i += stride) {
        int t = i / (NLEAF * FDIM / 4);
        int r = i % (NLEAF * FDIM / 4);
        int slot = r / (FDIM / 4);
        int kq = r % (FDIM / 4);
        int node = slot2node(slot);
        float4 v = ((const float4*)(W + ((size_t)t * NINT + node) * FDIM))[kq];
        u16x4 o = { f2bf(v.x), f2bf(v.y), f2bf(v.z), f2bf(v.w) };
        ((u16x4*)Wb)[i] = o;
    }
    if (idx < NTREE * NLEAF)
        bperm[idx] = b[(idx >> 6) * NINT + slot2node(idx & 63)];
}

// Block: 256 thr = 4 waves, each an INDEPENDENT tree (t = by*4 + wv) over the same
// 128 batch rows. x-tile (128x256, 64KB) DMA-staged ONCE; ONE __syncthreads total.
// W tree register-resident: wfr[4][8] (128 VGPR) loaded once and PINNED with
// asm volatile("" : "+v") so the compiler cannot rematerialize the loads into the
// K-loop (R9's silent failure: VGPR_Count=128 proved wfr was remat'd -> R8-style
// exposed global latency). Inner loop = ds_read_b128 + MFMA only. Bias folded
// into acc init. Epilogue: R6-verified register-only tree eval.
__global__ __launch_bounds__(256, 2) void softgbm_main(
    const u16* __restrict__ xb, const u16* __restrict__ Wb,
    const float* __restrict__ bperm, const float* __restrict__ phig,
    float* __restrict__ partial) {
    __shared__ u16 X[MT * FDIM];   // 64 KB, resident whole kernel

    const int tid = threadIdx.x;
    const int lane = tid & 63, wv = tid >> 6;
    const int t = blockIdx.y * 4 + wv;
    const int m0 = blockIdx.x * MT;
    const int frow = lane & 15, lg = lane >> 4, f7 = frow & 7;

    // ---- stage x-tile once: 4096 chunks, 16 issues/thread, pre-swizzled source
    #pragma unroll
    for (int i = 0; i < 16; ++i) {
        int cl = i * 256 + tid;
        int row = cl >> 5, pcc = cl & 31;
        int cc = (pcc & 24) | ((pcc & 7) ^ (row & 7));
        gload16(xb + (size_t)(m0 + row) * FDIM + cc * 8, &X[cl * 8]);
    }

    // ---- W fragments register-resident: slot = ar*16+frow, k = ks*32+lg*8
    const u16* wbase = Wb + (size_t)t * NLEAF * FDIM + frow * FDIM + lg * 8;
    bf16x8 wfr[4][8];
    #pragma unroll
    for (int ar = 0; ar < 4; ++ar)
        #pragma unroll
        for (int ks = 0; ks < 8; ++ks) {
            wfr[ar][ks] = *(const bf16x8*)(wbase + ar * 16 * FDIM + ks * 32);
            asm volatile("" : "+v"(wfr[ar][ks]));   // pin: forbid remat into loop
        }

    // ---- swizzled x-chunk byte offsets within a row's 512B (R7-verified)
    int xoff[8];
    #pragma unroll
    for (int ks = 0; ks < 8; ++ks) {
        int cx = ks * 4 + lg;
        xoff[ks] = ((cx & 24) | ((cx & 7) ^ f7)) * 16;
    }

    __syncthreads();   // X ready (also drains wfr loads); the ONLY barrier

    #pragma unroll
    for (int half = 0; half < 2; ++half) {
        // acc init = bias (slot ar*16+lg*4+j; same across bc). Kills z+bl add.
        f32x4 acc[4][4];
        #pragma unroll
        for (int ar = 0; ar < 4; ++ar)
            #pragma unroll
            for (int j = 0; j < 4; ++j) {
                float bv = bperm[t * 64 + ar * 16 + lg * 4 + j];
                #pragma unroll
                for (int bc = 0; bc < 4; ++bc) acc[ar][bc][j] = bv;
            }

        const char* Xc = (const char*)X;
        int rbase[4];
        #pragma unroll
        for (int bc = 0; bc < 4; ++bc)
            rbase[bc] = (half * 64 + bc * 16 + frow) * 512;

        __builtin_amdgcn_s_setprio(1);
        #pragma unroll
        for (int ks = 0; ks < 8; ++ks) {
            bf16x8 xf[4];
            #pragma unroll
            for (int bc = 0; bc < 4; ++bc)
                xf[bc] = *(const bf16x8*)(Xc + rbase[bc] + xoff[ks]);
            #pragma unroll
            for (int ar = 0; ar < 4; ++ar)
                #pragma unroll
                for (int bc = 0; bc < 4; ++bc)
                    acc[ar][bc] = __builtin_amdgcn_mfma_f32_16x16x32_bf16(wfr[ar][ks], xf[bc], acc[ar][bc], 0, 0, 0);
        }
        __builtin_amdgcn_s_setprio(0);

        // ---- in-register tree eval (R6-verified). Lane owns subtree lg.
        float pha[8], phd[8];
        #pragma unroll
        for (int i = 0; i < 8; ++i) {
            float2 p2 = *(const float2*)&phig[(size_t)t * NLEAF + lg * 16 + 2 * i];
            pha[i] = p2.x; phd[i] = p2.y - p2.x;
        }
        float tot[4];
        #pragma unroll
        for (int bc = 0; bc < 4; ++bc) {
            float pv[16];
            #pragma unroll
            for (int v2 = 0; v2 < 16; ++v2)
                pv[v2] = __builtin_amdgcn_rcpf(1.f + __expf(-acc[v2 >> 2][bc][v2 & 3]));
            float o = __shfl_xor(pv[0], 16);
            float proot = (lg & 1) ? o : pv[0];
            float pd1   = (lg & 1) ? pv[0] : o;
            float mb = ((lg >> 1) ? proot : 1.f - proot) * ((lg & 1) ? pd1 : 1.f - pd1);
            float m3[2], m4[4], m5[8];
            { float t1 = mb * pv[1]; m3[1] = t1; m3[0] = mb - t1; }
            #pragma unroll
            for (int i = 0; i < 2; ++i) { float t1 = m3[i] * pv[2 + i]; m4[2*i+1] = t1; m4[2*i] = m3[i] - t1; }
            #pragma unroll
            for (int i = 0; i < 4; ++i) { float t1 = m4[i] * pv[4 + i]; m5[2*i+1] = t1; m5[2*i] = m4[i] - t1; }
            float s = 0.f;
            #pragma unroll
            for (int i = 0; i < 8; ++i) s += m5[i] * (pha[i] + pv[8 + i] * phd[i]);
            s += __shfl_xor(s, 16);            // sum the 4 subtrees
            s += __shfl_xor(s, 32);
            tot[bc] = s;
        }
        // lane (lg,frow) holds row half*64 + lg*16 + frow = half*64 + lane via tot[lg]
        float vout = (lg & 2) ? ((lg & 1) ? tot[3] : tot[2])
                              : ((lg & 1) ? tot[1] : tot[0]);
        partial[(size_t)t * BATCH + m0 + half * 64 + lane] = vout;
    }
}

__global__ void reduce_kernel(const float* __restrict__ partial, float* __restrict__ out) {
    int i = blockIdx.x * 256 + threadIdx.x;
    float s = 0.f;
    #pragma unroll
    for (int t = 0; t < NTREE; ++t) s += partial[(size_t)t * BATCH + i];
    out[i] = 0.1f * s;
}

extern "C" void kernel_launch(void* const* d_in, const int* in_sizes, int n_in,
                              void* d_out, int out_size, void* d_ws, size_t ws_size,
                              hipStream_t stream) {
    const float* x   = (const float*)d_in[0];
    const float* W   = (const float*)d_in[1];
    const float* b   = (const float*)d_in[2];
    const float* phi = (const float*)d_in[3];
    float* out = (float*)d_out;

    u16* xb = (u16*)d_ws;                                  // 16384*256 bf16 = 8 MB
    u16* Wb = xb + (size_t)BATCH * FDIM;                   // 32*64*256 bf16 = 1 MB
    float* partial = (float*)(Wb + (size_t)NTREE * NLEAF * FDIM);  // 32*16384 f32 = 2 MB
    float* bperm = partial + (size_t)NTREE * BATCH;        // 32*64 f32 = 8 KB

    convert_kernel<<<2048, 256, 0, stream>>>(x, W, b, xb, Wb, bperm);
    softgbm_main<<<dim3(BATCH / MT, NTREE / 4), 256, 0, stream>>>(xb, Wb, bperm, phi, partial);
    reduce_kernel<<<BATCH / 256, 256, 0, stream>>>(partial, out);
}

// Round 12
// 39.643 us; speedup vs baseline: 1.2630x; 1.2630x over previous
//
#include <hip/hip_runtime.h>
#include <cmath>

typedef unsigned short u16;
typedef __bf16 bf16x8 __attribute__((ext_vector_type(8)));
typedef float f32x4 __attribute__((ext_vector_type(4)));
typedef unsigned short u16x4 __attribute__((ext_vector_type(4)));

#define BATCH 16384
#define NTREE 32
#define NINT 63
#define NLEAF 64
#define FDIM 256
#define MT 128     // batch rows per block
#define TPB 2      // trees per block
#define BK 32      // K per staging step (small -> 32KB total LDS -> 4+ blocks/CU)
#define KSTEPS 8   // 256/32

typedef __attribute__((address_space(3))) void lvoid;
typedef __attribute__((address_space(1))) const void gvoid;
__device__ __forceinline__ void gload16(const void* g, void* l) {
    // DMA 16B/lane global->LDS; LDS dest = wave-uniform base + lane*16 (HW rule)
    __builtin_amdgcn_global_load_lds((gvoid*)g, (lvoid*)l, 16, 0, 0);
}

__device__ __forceinline__ u16 f2bf(float f) {
    unsigned int x = __float_as_uint(f);
    x += 0x7fffu + ((x >> 16) & 1u);   // round-to-nearest-even
    return (u16)(x >> 16);
}

// D-row slot s (0..63) -> heap node id (R6-verified permutation).
__device__ __forceinline__ int slot2node(int slot) {
    int lg = (slot >> 2) & 3;
    int v = ((slot >> 4) << 2) | (slot & 3);
    if (v == 0)  return (lg & 1) ? (1 + (lg >> 1)) : 0;
    if (v == 1)  return 3 + lg;
    if (v < 4)   return 7 + 2 * lg + (v - 2);
    if (v < 8)   return 15 + 4 * lg + (v - 4);
    return 31 + 8 * lg + (v - 8);
}

__global__ void convert_kernel(const float* __restrict__ x, const float* __restrict__ W,
                               const float* __restrict__ b,
                               u16* __restrict__ xb, u16* __restrict__ Wb,
                               float* __restrict__ bperm) {
    int idx = blockIdx.x * blockDim.x + threadIdx.x;
    int stride = gridDim.x * blockDim.x;
    const int NXQ = BATCH * FDIM / 4;
    for (int i = idx; i < NXQ; i += stride) {
        float4 v = ((const float4*)x)[i];
        u16x4 o = { f2bf(v.x), f2bf(v.y), f2bf(v.z), f2bf(v.w) };
        ((u16x4*)xb)[i] = o;
    }
    // Wb: [tree][64 slots (permuted nodes, root duplicated)][256 features]
    const int NWQ = NTREE * NLEAF * FDIM / 4;
    for (int i = idx; i < NWQ; i += stride) {
        int t = i / (NLEAF * FDIM / 4);
        int r = i % (NLEAF * FDIM / 4);
        int slot = r / (FDIM / 4);
        int kq = r % (FDIM / 4);
        int node = slot2node(slot);
        float4 v = ((const float4*)(W + ((size_t)t * NINT + node) * FDIM))[kq];
        u16x4 o = { f2bf(v.x), f2bf(v.y), f2bf(v.z), f2bf(v.w) };
        ((u16x4*)Wb)[i] = o;
    }
    if (idx < NTREE * NLEAF)
        bperm[idx] = b[(idx >> 6) * NINT + slot2node(idx & 63)];
}

// Block: 256 thr = 4 waves, 128 batch rows x 2 trees (R6 geometry, best measured).
// Wave (tp=wv&1, rg=wv>>1): tree t0+tp's 64 slots x rows rg*64..+63; acc 4x4.
// SWAPPED GEMM: A = W slots, B = x rows. Double-buffered BK=32 step tiles:
// 2 x (8KB A + 8KB B) = 32KB total LDS -> with __launch_bounds__(256,4) (<=128
// VGPR) 4 blocks/CU resident = 16 waves/CU (2.7x R9's 6) — occupancy is the
// lever every prior round missed. One barrier/step, prefetch-after-barrier
// (R10-proven). Swizzle for BK=32 (4 chunks/row): cc ^ ((row>>1)&3) on BOTH the
// DMA global source and ds_read side -> exactly 2-way (free, m136).
// Bias folded into acc init (R9). Epilogue: R6-verified register-only tree eval.
__global__ __launch_bounds__(256, 4) void softgbm_main(
    const u16* __restrict__ xb, const u16* __restrict__ Wb,
    const float* __restrict__ bperm, const float* __restrict__ phig,
    float* __restrict__ partial) {
    __shared__ u16 Ash[2][MT * BK];   // 2 x 8KB: 2 trees x 64 slots, BK k
    __shared__ u16 Bsh[2][MT * BK];   // 2 x 8KB: 128 x-rows, BK k

    const int tid = threadIdx.x;
    const int lane = tid & 63, wv = tid >> 6;
    const int t0 = blockIdx.y * TPB;
    const int m0 = blockIdx.x * MT;
    const int tp = wv & 1, rg = wv >> 1;
    const int frow = lane & 15, lg = lane >> 4;
    const int t = t0 + tp;

    // ---- staging: 512 chunks per tile -> 2 chunks/thread; swizzled source
    const u16* agp[2]; const u16* bgp[2]; int ldst[2];
    #pragma unroll
    for (int j = 0; j < 2; ++j) {
        int cl = j * 256 + tid;
        int row = cl >> 2, p = cl & 3;
        int cc = p ^ ((row >> 1) & 3);              // involution per row
        agp[j] = Wb + (size_t)(t0 * NLEAF + row) * FDIM + cc * 8;
        bgp[j] = xb + (size_t)(m0 + row) * FDIM + cc * 8;
        ldst[j] = cl * 8;
    }

    // ---- frag read byte-offsets (same XOR on read side)
    int aoffs[4], boffs[4];
    #pragma unroll
    for (int ar = 0; ar < 4; ++ar) {
        int r = tp * 64 + ar * 16 + frow;
        aoffs[ar] = r * 64 + ((lg ^ ((r >> 1) & 3)) * 16);
    }
    #pragma unroll
    for (int bc = 0; bc < 4; ++bc) {
        int n = rg * 64 + bc * 16 + frow;
        boffs[bc] = n * 64 + ((lg ^ ((n >> 1) & 3)) * 16);
    }

    // ---- prologue: DMA step 0 into buf 0; tables; bias-folded acc init
    #pragma unroll
    for (int j = 0; j < 2; ++j) {
        gload16(agp[j], &Ash[0][ldst[j]]);
        gload16(bgp[j], &Bsh[0][ldst[j]]);
    }
    float pha[8], phd[8];
    #pragma unroll
    for (int i = 0; i < 8; ++i) {
        float2 p2 = *(const float2*)&phig[(size_t)t * NLEAF + lg * 16 + 2 * i];
        pha[i] = p2.x; phd[i] = p2.y - p2.x;
    }
    f32x4 acc[4][4];
    #pragma unroll
    for (int ar = 0; ar < 4; ++ar)
        #pragma unroll
        for (int j = 0; j < 4; ++j) {
            float bv = bperm[t * 64 + ar * 16 + lg * 4 + j];
            #pragma unroll
            for (int bc = 0; bc < 4; ++bc) acc[ar][bc][j] = bv;
        }

    // ---- K loop: 1 barrier/step; prefetch-after-barrier into the other buffer
    #pragma unroll
    for (int st = 0; st < KSTEPS; ++st) {
        __syncthreads();                 // buf[st&1] DMA (issued last step) done;
                                         // all waves finished reading other buf
        if (st < KSTEPS - 1) {
            #pragma unroll
            for (int j = 0; j < 2; ++j) {
                gload16(agp[j] + (st + 1) * BK, &Ash[(st + 1) & 1][ldst[j]]);
                gload16(bgp[j] + (st + 1) * BK, &Bsh[(st + 1) & 1][ldst[j]]);
            }
        }
        const char* Ab = (const char*)Ash[st & 1];
        const char* Bb = (const char*)Bsh[st & 1];
        bf16x8 af[4], bf_[4];
        #pragma unroll
        for (int ar = 0; ar < 4; ++ar) af[ar] = *(const bf16x8*)(Ab + aoffs[ar]);
        #pragma unroll
        for (int bc = 0; bc < 4; ++bc) bf_[bc] = *(const bf16x8*)(Bb + boffs[bc]);
        #pragma unroll
        for (int ar = 0; ar < 4; ++ar)
            #pragma unroll
            for (int bc = 0; bc < 4; ++bc)
                acc[ar][bc] = __builtin_amdgcn_mfma_f32_16x16x32_bf16(af[ar], bf_[bc], acc[ar][bc], 0, 0, 0);
    }

    // ---- in-register tree eval (R6-verified). Lane owns subtree lg.
    float tot[4];
    #pragma unroll
    for (int bc = 0; bc < 4; ++bc) {
        float pv[16];
        #pragma unroll
        for (int v2 = 0; v2 < 16; ++v2)
            pv[v2] = __builtin_amdgcn_rcpf(1.f + __expf(-acc[v2 >> 2][bc][v2 & 3]));
        float o = __shfl_xor(pv[0], 16);
        float proot = (lg & 1) ? o : pv[0];
        float pd1   = (lg & 1) ? pv[0] : o;
        float mb = ((lg >> 1) ? proot : 1.f - proot) * ((lg & 1) ? pd1 : 1.f - pd1);
        float m3[2], m4[4], m5[8];
        { float t1 = mb * pv[1]; m3[1] = t1; m3[0] = mb - t1; }
        #pragma unroll
        for (int i = 0; i < 2; ++i) { float t1 = m3[i] * pv[2 + i]; m4[2*i+1] = t1; m4[2*i] = m3[i] - t1; }
        #pragma unroll
        for (int i = 0; i < 4; ++i) { float t1 = m4[i] * pv[4 + i]; m5[2*i+1] = t1; m5[2*i] = m4[i] - t1; }
        float s = 0.f;
        #pragma unroll
        for (int i = 0; i < 8; ++i) s += m5[i] * (pha[i] + pv[8 + i] * phd[i]);
        s += __shfl_xor(s, 16);            // sum the 4 subtrees
        s += __shfl_xor(s, 32);
        tot[bc] = s;
    }
    // lane (lg,frow): row rg*64 + lg*16 + frow = rg*64 + lane, value tot[lg]
    float vout = (lg & 2) ? ((lg & 1) ? tot[3] : tot[2])
                          : ((lg & 1) ? tot[1] : tot[0]);
    partial[(size_t)t * BATCH + m0 + rg * 64 + lane] = vout;
}

__global__ void reduce_kernel(const float* __restrict__ partial, float* __restrict__ out) {
    int i = blockIdx.x * 256 + threadIdx.x;
    float s = 0.f;
    #pragma unroll
    for (int t = 0; t < NTREE; ++t) s += partial[(size_t)t * BATCH + i];
    out[i] = 0.1f * s;
}

extern "C" void kernel_launch(void* const* d_in, const int* in_sizes, int n_in,
                              void* d_out, int out_size, void* d_ws, size_t ws_size,
                              hipStream_t stream) {
    const float* x   = (const float*)d_in[0];
    const float* W   = (const float*)d_in[1];
    const float* b   = (const float*)d_in[2];
    const float* phi = (const float*)d_in[3];
    float* out = (float*)d_out;

    u16* xb = (u16*)d_ws;                                  // 16384*256 bf16 = 8 MB
    u16* Wb = xb + (size_t)BATCH * FDIM;                   // 32*64*256 bf16 = 1 MB
    float* partial = (float*)(Wb + (size_t)NTREE * NLEAF * FDIM);  // 32*16384 f32 = 2 MB
    float* bperm = partial + (size_t)NTREE * BATCH;        // 32*64 f32 = 8 KB

    convert_kernel<<<2048, 256, 0, stream>>>(x, W, b, xb, Wb, bperm);
    softgbm_main<<<dim3(BATCH / MT, NTREE / TPB), 256, 0, stream>>>(xb, Wb, bperm, phi, partial);
    reduce_kernel<<<BATCH / 256, 256, 0, stream>>>(partial, out);
}